// Round 1
// baseline (640.210 us; speedup 1.0000x reference)
//
#include <hip/hip_runtime.h>

// SelfAttention (Transformer-XL style) on gfx950.
// Pipeline: convert->bf16, GEMM1 (qkv), RoPE prep, flash attention, GEMM2 (dense).
// All matmuls: bf16 MFMA 16x16x32, f32 accumulate. Threshold is 8 bf16-ulps -> bf16 OK.

typedef __attribute__((ext_vector_type(4))) float f32x4;
typedef __attribute__((ext_vector_type(8))) short bf16x8;
typedef unsigned short u16;

#define SQ   1024
#define BSZ  2
#define H    4096
#define NH   32
#define HD   128
#define MEML 1024
#define KV   2048
#define NHEADS 64   // BSZ*NH

__device__ __forceinline__ u16 f32_to_bf16(float f) {
  union { float f; unsigned int u; } v; v.f = f;
  unsigned int r = v.u + 0x7FFFu + ((v.u >> 16) & 1u);
  return (u16)(r >> 16);
}

__device__ __forceinline__ void gload_lds16(const void* g, void* l) {
  __builtin_amdgcn_global_load_lds((const __attribute__((address_space(1))) void*)g,
                                   (__attribute__((address_space(3))) void*)l, 16, 0, 0);
}

// ---------------- f32 -> bf16 convert (vectorized) ----------------
__global__ __launch_bounds__(256) void conv_bf16(const float* __restrict__ in,
                                                 u16* __restrict__ out, int n4) {
  int idx = blockIdx.x * 256 + threadIdx.x;
  if (idx < n4) {
    float4 v = ((const float4*)in)[idx];
    ushort4 o;
    o.x = f32_to_bf16(v.x); o.y = f32_to_bf16(v.y);
    o.z = f32_to_bf16(v.z); o.w = f32_to_bf16(v.w);
    ((ushort4*)out)[idx] = o;
  }
}

// ---------------- RoPE tables: cos/sin[s][j], pos = MEM_LEN + s ----------------
__global__ __launch_bounds__(256) void rope_tables(float* __restrict__ cost, float* __restrict__ sint) {
  int idx = blockIdx.x * 256 + threadIdx.x;   // 65536 = 1024 s * 64 j
  int s = idx >> 6, j = idx & 63;
  float inv = powf(10000.0f, -(float)j / 64.0f);
  float ang = (float)(MEML + s) * inv;
  cost[idx] = cosf(ang);
  sint[idx] = sinf(ang);
}

// ---------------- GEMM: C[M,N] = A[M,K](bf16) * B[N,K]^T(bf16) + bias[N], f32 out ----
// 128x128 tile, BK=64, 256 threads (4 waves 2x2), global_load_lds w/ XOR swizzle.
__global__ __launch_bounds__(256) void gemm_bt(const u16* __restrict__ A, const u16* __restrict__ B,
                                               const float* __restrict__ bias, float* __restrict__ C,
                                               int N, int K) {
  __shared__ u16 As[128 * 64];
  __shared__ u16 Bs[128 * 64];
  const int tid = threadIdx.x;
  const int lane = tid & 63;
  const int w = tid >> 6;
  const int wm = w >> 1, wn = w & 1;
  const int m0 = blockIdx.y * 128, n0 = blockIdx.x * 128;
  const int rl = lane & 15, cg = lane >> 4;

  f32x4 acc[4][4];
#pragma unroll
  for (int i = 0; i < 4; ++i)
#pragma unroll
    for (int j = 0; j < 4; ++j) acc[i][j] = (f32x4){0.f, 0.f, 0.f, 0.f};

  for (int k0 = 0; k0 < K; k0 += 64) {
#pragma unroll
    for (int i = 0; i < 4; ++i) {
      int flat = i * 256 + tid;          // 1024 slots of 16B per tile
      int row = flat >> 3;
      int cb = (flat & 7) << 4;
      int scb = cb ^ ((row & 7) << 4);   // inverse-swizzled global source (rule #21)
      gload_lds16((const char*)(A + (size_t)(m0 + row) * K + k0) + scb,
                  (char*)As + (flat << 4));
      gload_lds16((const char*)(B + (size_t)(n0 + row) * K + k0) + scb,
                  (char*)Bs + (flat << 4));
    }
    __syncthreads();
#pragma unroll
    for (int kk = 0; kk < 2; ++kk) {
      bf16x8 af[4], bfr[4];
#pragma unroll
      for (int mi = 0; mi < 4; ++mi) {
        int row = wm * 64 + mi * 16 + rl;
        int cb = (kk * 64 + cg * 16) ^ ((row & 7) << 4);
        af[mi] = *(const bf16x8*)((const char*)As + row * 128 + cb);
      }
#pragma unroll
      for (int ni = 0; ni < 4; ++ni) {
        int row = wn * 64 + ni * 16 + rl;
        int cb = (kk * 64 + cg * 16) ^ ((row & 7) << 4);
        bfr[ni] = *(const bf16x8*)((const char*)Bs + row * 128 + cb);
      }
#pragma unroll
      for (int mi = 0; mi < 4; ++mi)
#pragma unroll
        for (int ni = 0; ni < 4; ++ni)
          acc[mi][ni] = __builtin_amdgcn_mfma_f32_16x16x32_bf16(af[mi], bfr[ni], acc[mi][ni], 0, 0, 0);
    }
    __syncthreads();
  }
  // epilogue: C layout col=lane&15, row=(lane>>4)*4+j  [m89]
#pragma unroll
  for (int ni = 0; ni < 4; ++ni) {
    int col = n0 + wn * 64 + ni * 16 + rl;
    float bv = bias[col];
#pragma unroll
    for (int mi = 0; mi < 4; ++mi) {
      int rbase = m0 + wm * 64 + mi * 16 + cg * 4;
#pragma unroll
      for (int j = 0; j < 4; ++j)
        C[(size_t)(rbase + j) * N + col] = acc[mi][ni][j] + bv;
    }
  }
}

// ---------------- prep: roped Q (scaled 1/sqrt(HD)) and roped new-K ----------------
// mixed layout: row (s*2+b), col o = nh*384 + part*128 + d  (part 0=q,1=k,2=v)
__global__ __launch_bounds__(256) void prep_qk(const float* __restrict__ mixed,
                                               const float* __restrict__ cost,
                                               const float* __restrict__ sint,
                                               u16* __restrict__ Qb, u16* __restrict__ Kb) {
  int s0 = blockIdx.x * 64, head = blockIdx.y;
  int b = head >> 5, nh = head & 31;
  int tid = threadIdx.x;
  const float qs = 0.08838834764831845f;  // 1/sqrt(128); coeff cancels except in mask constant
#pragma unroll
  for (int i = 0; i < 16; ++i) {
    int flat = i * 256 + tid;    // 4096 = 64 s * 64 j
    int sl = flat >> 6, j = flat & 63;
    int s = s0 + sl;
    size_t base = ((size_t)(s * 2 + b)) * 12288 + (size_t)nh * 384;
    float q1 = mixed[base + j],       q2 = mixed[base + j + 64];
    float k1 = mixed[base + 128 + j], k2 = mixed[base + 192 + j];
    float c = cost[s * 64 + j], sn = sint[s * 64 + j];
    float q1r = q1 * c - q2 * sn, q2r = q2 * c + q1 * sn;
    float k1r = k1 * c - k2 * sn, k2r = k2 * c + k1 * sn;
    size_t qoff = ((size_t)head * SQ + s) * HD;
    Qb[qoff + j]      = f32_to_bf16(q1r * qs);
    Qb[qoff + j + 64] = f32_to_bf16(q2r * qs);
    size_t koff = ((size_t)head * KV + MEML + s) * HD;
    Kb[koff + j]      = f32_to_bf16(k1r);
    Kb[koff + j + 64] = f32_to_bf16(k2r);
  }
}

// ---------------- prep: mem-K copy + V (mem & new) transposed per head ----------------
__global__ __launch_bounds__(256) void prep_kv(const float* __restrict__ mixed,
                                               const float* __restrict__ mem,
                                               u16* __restrict__ Kb, u16* __restrict__ Vtb) {
  int t0 = blockIdx.x * 64, head = blockIdx.y;
  int b = head >> 5, nh = head & 31;
  __shared__ u16 vt[128 * 72];   // padded for 16B-aligned transposed rows
  int tid = threadIdx.x;
  if (t0 < MEML) {
#pragma unroll
    for (int i = 0; i < 32; ++i) {
      int flat = i * 256 + tid;   // 8192 = 64 t * 128 d
      int tl = flat >> 7, d = flat & 127;
      float kvv = mem[((size_t)b * MEML + t0 + tl) * 8192 + (size_t)nh * HD + d];
      Kb[((size_t)head * KV + t0 + tl) * HD + d] = f32_to_bf16(kvv);
    }
  }
#pragma unroll
  for (int i = 0; i < 32; ++i) {
    int flat = i * 256 + tid;
    int tl = flat >> 7, d = flat & 127;
    int t = t0 + tl;
    float v;
    if (t < MEML) v = mem[((size_t)b * MEML + t) * 8192 + 4096 + (size_t)nh * HD + d];
    else          v = mixed[((size_t)((t - MEML) * 2 + b)) * 12288 + (size_t)nh * 384 + 256 + d];
    vt[d * 72 + tl] = f32_to_bf16(v);
  }
  __syncthreads();
#pragma unroll
  for (int i = 0; i < 4; ++i) {
    int c = i * 256 + tid;        // 1024 chunks of 8 elems
    int d = c >> 3, slot = c & 7;
    *(bf16x8*)(Vtb + ((size_t)head * HD + d) * KV + t0 + slot * 8) =
        *(const bf16x8*)(vt + d * 72 + slot * 8);
  }
}

// ---------------- flash attention ----------------
// grid (16 q-tiles, 64 heads), 256 threads = 4 waves; wave w owns q rows q0+w*16..+15.
__global__ __launch_bounds__(256) void attn_fwd(const u16* __restrict__ Qb, const u16* __restrict__ Kb,
                                                const u16* __restrict__ Vtb, u16* __restrict__ ctx) {
  __shared__ u16 Ks[64 * 128];    // [t][k] 256B rows, XOR-swizzled
  __shared__ u16 Vts[128 * 64];   // [d][t] 128B rows, XOR-swizzled
  __shared__ u16 Ps[4 * 16 * 64]; // per-wave P tile, XOR-swizzled
  const int tid = threadIdx.x;
  const int lane = tid & 63;
  const int w = tid >> 6;
  const int q0 = blockIdx.x * 64;
  const int head = blockIdx.y;
  const int rl = lane & 15, cg = lane >> 4;

  bf16x8 qf[4];
  {
    const u16* Qrow = Qb + ((size_t)head * SQ + q0 + w * 16 + rl) * HD;
#pragma unroll
    for (int kk = 0; kk < 4; ++kk)
      qf[kk] = *(const bf16x8*)(Qrow + kk * 32 + cg * 8);
  }

  f32x4 acc[8];
#pragma unroll
  for (int i = 0; i < 8; ++i) acc[i] = (f32x4){0.f, 0.f, 0.f, 0.f};
  float mrow[4] = {-3.0e38f, -3.0e38f, -3.0e38f, -3.0e38f};
  float lrow[4] = {0.f, 0.f, 0.f, 0.f};

  const int t_end = q0 + 64 + MEML;   // max allowed t (exclusive); <= 2048 always

  for (int t0 = 0; t0 < t_end; t0 += 64) {
    // stage K tile (64 x 128 bf16; 256B rows, 16 slots)
#pragma unroll
    for (int i = 0; i < 4; ++i) {
      int flat = i * 256 + tid;
      int row = flat >> 4;
      int cb = (flat & 15) << 4;
      int scb = cb ^ ((row & 7) << 4);
      gload_lds16((const char*)(Kb + ((size_t)head * KV + t0 + row) * HD) + scb,
                  (char*)Ks + (flat << 4));
    }
    // stage Vt tile (128 x 64 bf16; 128B rows, 8 slots)
#pragma unroll
    for (int i = 0; i < 4; ++i) {
      int flat = i * 256 + tid;
      int row = flat >> 3;
      int cb = (flat & 7) << 4;
      int scb = cb ^ ((row & 7) << 4);
      gload_lds16((const char*)(Vtb + ((size_t)head * HD + row) * KV + t0) + scb,
                  (char*)Vts + (flat << 4));
    }
    __syncthreads();

    // S = Q K^T / sqrt(HD)  (Q prescaled)
    f32x4 sf[4];
#pragma unroll
    for (int tn = 0; tn < 4; ++tn) {
      f32x4 s = (f32x4){0.f, 0.f, 0.f, 0.f};
#pragma unroll
      for (int kk = 0; kk < 4; ++kk) {
        int row = tn * 16 + rl;
        int cb = (kk * 64 + cg * 16) ^ ((row & 7) << 4);
        bf16x8 kf = *(const bf16x8*)((const char*)Ks + row * 256 + cb);
        s = __builtin_amdgcn_mfma_f32_16x16x32_bf16(qf[kk], kf, s, 0, 0, 0);
      }
      sf[tn] = s;
    }
    // mask: allowed t <= s + MEML ; masked value = -10000*coeff = -40000
    if (t0 + 63 > MEML + q0 + w * 16) {
#pragma unroll
      for (int tn = 0; tn < 4; ++tn)
#pragma unroll
        for (int j = 0; j < 4; ++j) {
          int t = t0 + tn * 16 + rl;
          int srow = q0 + w * 16 + cg * 4 + j;
          if (t - MEML > srow) sf[tn][j] = -40000.0f;
        }
    }
    // online softmax (rows live in 16-lane column groups: reduce over rl)
    float mt[4];
#pragma unroll
    for (int j = 0; j < 4; ++j)
      mt[j] = fmaxf(fmaxf(sf[0][j], sf[1][j]), fmaxf(sf[2][j], sf[3][j]));
#pragma unroll
    for (int off = 1; off <= 8; off <<= 1)
#pragma unroll
      for (int j = 0; j < 4; ++j) mt[j] = fmaxf(mt[j], __shfl_xor(mt[j], off, 64));
    float pscale[4];
#pragma unroll
    for (int j = 0; j < 4; ++j) {
      float mn = fmaxf(mrow[j], mt[j]);
      pscale[j] = __expf(mrow[j] - mn);
      mrow[j] = mn;
    }
    float lsum[4] = {0.f, 0.f, 0.f, 0.f};
#pragma unroll
    for (int tn = 0; tn < 4; ++tn)
#pragma unroll
      for (int j = 0; j < 4; ++j) {
        float p = __expf(sf[tn][j] - mrow[j]);
        lsum[j] += p;
        int prow = cg * 4 + j;
        int colb = (tn * 16 + rl) * 2;
        int addr = w * 2048 + prow * 128 + (colb ^ ((prow & 7) << 4));
        *(u16*)((char*)Ps + addr) = f32_to_bf16(p);
      }
#pragma unroll
    for (int off = 1; off <= 8; off <<= 1)
#pragma unroll
      for (int j = 0; j < 4; ++j) lsum[j] += __shfl_xor(lsum[j], off, 64);
#pragma unroll
    for (int j = 0; j < 4; ++j) lrow[j] = lrow[j] * pscale[j] + lsum[j];
#pragma unroll
    for (int dn = 0; dn < 8; ++dn)
#pragma unroll
      for (int j = 0; j < 4; ++j) acc[dn][j] *= pscale[j];
    // PV: ctx += P * V   (A=P from per-wave LDS, B=V via Vt rows)
#pragma unroll
    for (int dn = 0; dn < 8; ++dn) {
#pragma unroll
      for (int kk2 = 0; kk2 < 2; ++kk2) {
        int pcb = (kk2 * 64 + cg * 16) ^ ((rl & 7) << 4);
        bf16x8 pf = *(const bf16x8*)((const char*)Ps + w * 2048 + rl * 128 + pcb);
        int vrow = dn * 16 + rl;
        int vcb = (kk2 * 64 + cg * 16) ^ ((vrow & 7) << 4);
        bf16x8 vf = *(const bf16x8*)((const char*)Vts + vrow * 128 + vcb);
        acc[dn] = __builtin_amdgcn_mfma_f32_16x16x32_bf16(pf, vf, acc[dn], 0, 0, 0);
      }
    }
    __syncthreads();
  }
  // epilogue: ctx[(s*2+b)][nh*128+d] bf16
  const int b = head >> 5, nh = head & 31;
#pragma unroll
  for (int dn = 0; dn < 8; ++dn)
#pragma unroll
    for (int j = 0; j < 4; ++j) {
      int srow = q0 + w * 16 + cg * 4 + j;
      float v = acc[dn][j] / lrow[j];
      ctx[((size_t)(srow * 2 + b)) * H + (size_t)nh * HD + dn * 16 + rl] = f32_to_bf16(v);
    }
}

// ---------------- launch ----------------
extern "C" void kernel_launch(void* const* d_in, const int* in_sizes, int n_in,
                              void* d_out, int out_size, void* d_ws, size_t ws_size,
                              hipStream_t stream) {
  const float* hidden  = (const float*)d_in[0];
  const float* mem     = (const float*)d_in[3];
  const float* qkv_w   = (const float*)d_in[4];
  const float* qkv_b   = (const float*)d_in[5];
  const float* dense_w = (const float*)d_in[6];
  const float* dense_b = (const float*)d_in[7];
  float* out = (float*)d_out;
  char* ws = (char*)d_ws;

  // workspace layout (total ~224.5 MiB)
  float* mixed = (float*)ws;                      // 100,663,296 B (2048x12288 f32)
  char* R1 = ws + 100663296;
  u16* hid_bf = (u16*)R1;                         // 16,777,216 B (until GEMM1 done)
  u16* qw_bf  = (u16*)(R1 + 16777216);            // 100,663,296 B (until GEMM1 done)
  u16* Qb  = (u16*)R1;                            // 16,777,216 B  [64][1024][128]
  u16* Kb  = (u16*)(R1 + 16777216);               // 33,554,432 B  [64][2048][128]
  u16* Vtb = (u16*)(R1 + 50331648);               // 33,554,432 B  [64][128][2048]
  u16* ctx = (u16*)(R1 + 83886080);               // 16,777,216 B  [2048][4096]
  u16* dw_bf = (u16*)(R1 + 100663296);            // 33,554,432 B
  float* cost = (float*)(ws + 234881024);         // 262,144 B
  float* sint = (float*)(ws + 234881024 + 262144);

  conv_bf16<<<8192, 256, 0, stream>>>(hidden, hid_bf, 2097152);
  conv_bf16<<<49152, 256, 0, stream>>>(qkv_w, qw_bf, 12582912);
  rope_tables<<<256, 256, 0, stream>>>(cost, sint);
  gemm_bt<<<dim3(96, 16), 256, 0, stream>>>(hid_bf, qw_bf, qkv_b, mixed, 12288, 4096);
  prep_qk<<<dim3(16, 64), 256, 0, stream>>>(mixed, cost, sint, Qb, Kb);
  prep_kv<<<dim3(32, 64), 256, 0, stream>>>(mixed, mem, Kb, Vtb);
  conv_bf16<<<16384, 256, 0, stream>>>(dense_w, dw_bf, 4194304);
  attn_fwd<<<dim3(16, 64), 256, 0, stream>>>(Qb, Kb, Vtb, ctx);
  gemm_bt<<<dim3(32, 16), 256, 0, stream>>>(ctx, dw_bf, dense_b, out, 4096, 4096);
}